// Round 10
// baseline (337.708 us; speedup 1.0000x reference)
//
#include <hip/hip_runtime.h>

using i32x4 = __attribute__((ext_vector_type(4))) int;

// ws layout (bytes); total = 41,629,696 B
#define OFF_STATS  0u         // 1024 x u64: [0..511] conv1 (s1,s2), [512..1023] conv2
#define OFF_SCALES 8192u      // 512 f32
#define OFF_AB     10240u     // 1024 f32
#define OFF_WPK1   14336u     // 589824 B int8
#define OFF_WPK2   604160u    // 589824 B int8
#define OFF_SPAD   1193984u   // 64*30*30*256 int8 = 14,745,600 B
#define OFF_COUT   15939584u  // 64*256*28*28 int16 = 25,690,112 B
#define SPAD_BYTES (64ull * 30 * 30 * 256)

__device__ __forceinline__ char sgn8(float v) {
  return v > 0.f ? (char)1 : (v < 0.f ? (char)-1 : (char)0);
}

// pack sign(w) into i8-MFMA A-fragment order: [khw][cc][mb][lane][i]
// o = mb*16 + (lane&15), c = cc*64 + (lane>>4)*16 + i  (mirrors B's NHWC layout)
__global__ __launch_bounds__(256) void k_wprep(const float* __restrict__ w,
                                               char* __restrict__ wp) {
  int idx  = blockIdx.x * 256 + threadIdx.x;  // < 589824
  int i    = idx & 15;
  int lane = (idx >> 4) & 63;
  int mb   = (idx >> 10) & 15;
  int cc   = (idx >> 14) & 3;
  int khw  = idx >> 16;
  int o = mb * 16 + (lane & 15);
  int c = cc * 64 + (lane >> 4) * 16 + i;
  int kh = khw / 3, kw = khw % 3;
  float v = w[(((size_t)o * 256 + c) * 3 + kh) * 3 + kw];
  wp[idx] = sgn8(v);
}

__global__ __launch_bounds__(256) void k_scale(const float* __restrict__ w,
                                               float* __restrict__ sc) {
  int o = blockIdx.x;
  float s = 0.f;
  for (int i = threadIdx.x; i < 2304; i += 256) s += fabsf(w[(size_t)o * 2304 + i]);
  for (int m = 1; m < 64; m <<= 1) s += __shfl_xor(s, m);
  __shared__ float red[4];
  if ((threadIdx.x & 63) == 0) red[threadIdx.x >> 6] = s;
  __syncthreads();
  if (threadIdx.x == 0) sc[o] = (red[0] + red[1] + red[2] + red[3]) * (1.f / 2304.f);
}

// sign(x + b10) -> padded NHWC int8 sign tensor [64][30][30][256] (border stays 0)
__global__ __launch_bounds__(256) void k_e0(const float* __restrict__ x,
                                            const float* __restrict__ b10,
                                            char* __restrict__ sp) {
  __shared__ char lds[28 * 260];
  int img = blockIdx.x / 28, y = blockIdx.x % 28;
  int t = threadIdx.x;
  int xx = t & 31, ci = t >> 5;
  for (int c0 = 0; c0 < 256; c0 += 8) {
    int c = c0 + ci;
    if (xx < 28) {
      float v = x[(((size_t)img * 256 + c) * 28 + y) * 28 + xx] + b10[c];
      lds[xx * 260 + c] = sgn8(v);
    }
  }
  __syncthreads();
  size_t base = (((size_t)img * 30 + (y + 1)) * 30 + 1) * 256;  // byte offset
  int* spi = (int*)(sp + base);
  for (int q = t; q < 1792; q += 256) {
    int xo = q >> 6, c4 = (q & 63) << 2;
    spi[q] = *(const int*)&lds[xo * 260 + c4];
  }
}

// binary conv as implicit GEMM with i8 MFMA (exact int32 counts).
// Block = 1 image x 2 output rows (56 px) x 256 out-ch. 8 waves; wave =
// 32 out-ch x 56 px (j=0..3, p>=56 lanes masked at store/stats). S-tile =
// 4 padded rows (4x30x256 = 30KB) in LDS -> grid 896 = 3.5 blocks/CU,
// LDS admits 5 -> target 24-28 waves/CU (round 9 measured only 10 at the
// 448-block/46KB geometry).
// Exact swizzle: stored granule g' = g ^ k(tp), k(tp) = (tp-2*(tp/30))&15
// == (28*row+col)&15; read key (l15+12*kh+kw)&15 == k(tp) along every
// fragment -> bijective per 16-lane group => conflict-light ds_read_b128.
// __launch_bounds__(512,4) is REQUIRED with the 30KB tile: without it the
// LDS-driven occupancy heuristic targets 8 waves/EU, caps VGPR at 40 and
// spills acc (rounds 6/7: WRITE_SIZE +11MB, 117-124us). (512,4) -> cap 128,
// round 9 proved the same body compiles to 64 VGPR spill-free.
__global__ __launch_bounds__(512, 4) void k_conv(const char* __restrict__ S,
                                                 const char* __restrict__ Wp,
                                                 short* __restrict__ C,
                                                 unsigned long long* __restrict__ stats) {
  __shared__ char lds[30720];
  int bid = blockIdx.x;            // 896 = 64 img * 14 ytile
  int img = bid / 14;
  int yt  = bid % 14;
  int tid = threadIdx.x;
  int wave = tid >> 6, lane = tid & 63;
  int l15 = lane & 15, lg = lane >> 4;
  int y0 = yt * 2;

  // stage 4 padded rows y0..y0+3 (local tp = row*30+col, 120 px x 16 granules)
  const char* sb = S + (size_t)img * 230400 + (size_t)y0 * 7680;
  for (int q = tid; q < 1920; q += 512) {
    int tp = q >> 4;
    int g  = q & 15;
    int k  = (tp - 2 * (tp / 30)) & 15;   // == (28*row + col) & 15
    int4 v = *reinterpret_cast<const int4*>(sb + tp * 256 + g * 16);
    *reinterpret_cast<int4*>(&lds[tp * 256 + ((g ^ k) << 4)]) = v;
  }
  __syncthreads();

  int pixtp[4];
#pragma unroll
  for (int j = 0; j < 4; ++j) {
    int p = j * 16 + l15;
    int pc = p < 56 ? p : 55;     // clamp masked lanes (keeps LDS reads in-bounds)
    pixtp[j] = (pc / 28) * 30 + (pc % 28);
  }
  i32x4 acc[2][4] = {};

#pragma unroll 1
  for (int kh = 0; kh < 3; ++kh) {
#pragma unroll
    for (int kw = 0; kw < 3; ++kw) {
      int khw = kh * 3 + kw;
      int shift = kh * 30 + kw;
      int kk = (l15 + 12 * kh + kw) & 15;
      const char* ab = Wp + (size_t)khw * 65536 + (size_t)wave * 2048 + lane * 16;
#pragma unroll
      for (int cc = 0; cc < 4; ++cc) {
        i32x4 afr[2];
        afr[0] = *reinterpret_cast<const i32x4*>(ab + cc * 16384);
        afr[1] = *reinterpret_cast<const i32x4*>(ab + cc * 16384 + 1024);
        int gr = (lg + 4 * cc) ^ kk;
        i32x4 bfr[4];
#pragma unroll
        for (int j = 0; j < 4; ++j) {
          int tp = pixtp[j] + shift;
          bfr[j] = *reinterpret_cast<const i32x4*>(&lds[tp * 256 + (gr << 4)]);
        }
#pragma unroll
        for (int mi = 0; mi < 2; ++mi)
#pragma unroll
          for (int j = 0; j < 4; ++j)
            acc[mi][j] = __builtin_amdgcn_mfma_i32_16x16x64_i8(afr[mi], bfr[j], acc[mi][j], 0, 0, 0);
      }
    }
  }

  short* cb = C + (size_t)img * 200704;
#pragma unroll
  for (int mi = 0; mi < 2; ++mi) {
#pragma unroll
    for (int r = 0; r < 4; ++r) {
      int o = wave * 32 + mi * 16 + lg * 4 + r;
      int s1 = 0;
      long long s2 = 0;
#pragma unroll
      for (int j = 0; j < 4; ++j) {
        int p = j * 16 + l15;
        if (p < 56) {
          int iv = acc[mi][j][r];
          cb[(size_t)o * 784 + (y0 + p / 28) * 28 + (p % 28)] = (short)iv;
          s1 += iv;
          s2 += (long long)iv * iv;
        }
      }
      long long t1 = s1, t2 = s2;
#pragma unroll
      for (int m = 1; m < 16; m <<= 1) {
        t1 += __shfl_xor(t1, m);
        t2 += __shfl_xor(t2, m);
      }
      if (l15 == 0) {
        atomicAdd(&stats[o], (unsigned long long)t1);
        atomicAdd(&stats[256 + o], (unsigned long long)t2);
      }
    }
  }
}

// fold scale + BN(train) into per-channel affine: bn(scale*I) = A*I + B
__global__ void k_bnprep(const unsigned long long* __restrict__ stats,
                         const float* __restrict__ scale,
                         const float* __restrict__ gamma,
                         const float* __restrict__ beta,
                         float* __restrict__ AB) {
  int o = threadIdx.x;
  long long s1 = (long long)stats[o];
  long long s2 = (long long)stats[256 + o];
  double n  = 50176.0;
  double sc = (double)scale[o];
  double mI = (double)s1 / n;
  double vI = (double)s2 / n - mI * mI;
  double mu  = sc * mI;
  double var = sc * sc * vI;
  double r = 1.0 / sqrt(var + 1e-5);
  double g = (double)gamma[o];
  AB[o]       = (float)(g * sc * r);
  AB[256 + o] = (float)((double)beta[o] - g * r * mu);
}

// h = prelu(bn1(c1) + x + b11, a1) + b12 -> d_out; sign(h+b20) -> spad
__global__ __launch_bounds__(256) void k_e1(const short* __restrict__ c1,
                                            const float* __restrict__ x,
                                            const float* __restrict__ AB,
                                            const float* __restrict__ b11,
                                            const float* __restrict__ a1,
                                            const float* __restrict__ b12,
                                            const float* __restrict__ b20,
                                            float* __restrict__ ho,
                                            char* __restrict__ sp) {
  __shared__ char lds[28 * 260];
  int img = blockIdx.x / 28, y = blockIdx.x % 28;
  int t = threadIdx.x;
  int xx = t & 31, ci = t >> 5;
  for (int c0 = 0; c0 < 256; c0 += 8) {
    int c = c0 + ci;
    if (xx < 28) {
      size_t off = (((size_t)img * 256 + c) * 28 + y) * 28 + xx;
      float h = AB[c] * (float)c1[off] + AB[256 + c] + x[off] + b11[c];
      h = h >= 0.f ? h : a1[c] * h;
      h += b12[c];
      ho[off] = h;
      lds[xx * 260 + c] = sgn8(h + b20[c]);
    }
  }
  __syncthreads();
  size_t base = (((size_t)img * 30 + (y + 1)) * 30 + 1) * 256;
  int* spi = (int*)(sp + base);
  for (int q = t; q < 1792; q += 256) {
    int xo = q >> 6, c4 = (q & 63) << 2;
    spi[q] = *(const int*)&lds[xo * 260 + c4];
  }
}

// y = prelu(bn2(c2) + h + b21, a2) + b22, in place on d_out (h)
__global__ __launch_bounds__(256) void k_e2(const short* __restrict__ c2,
                                            const float* __restrict__ AB2,
                                            const float* __restrict__ b21,
                                            const float* __restrict__ a2,
                                            const float* __restrict__ b22,
                                            float* __restrict__ io) {
  int v = blockIdx.x * 256 + threadIdx.x;  // < 3211264 float4s
  int c = ((v * 4) / 784) & 255;
  float A = AB2[c], B = AB2[256 + c];
  float p21 = b21[c], aa = a2[c], p22 = b22[c];
  short4 I = reinterpret_cast<const short4*>(c2)[v];
  float4 h = reinterpret_cast<const float4*>(io)[v];
  float4 r;
  float t0 = A * (float)I.x + B + h.x + p21; t0 = t0 >= 0.f ? t0 : aa * t0; r.x = t0 + p22;
  float t1 = A * (float)I.y + B + h.y + p21; t1 = t1 >= 0.f ? t1 : aa * t1; r.y = t1 + p22;
  float t2 = A * (float)I.z + B + h.z + p21; t2 = t2 >= 0.f ? t2 : aa * t2; r.z = t2 + p22;
  float t3 = A * (float)I.w + B + h.w + p21; t3 = t3 >= 0.f ? t3 : aa * t3; r.w = t3 + p22;
  reinterpret_cast<float4*>(io)[v] = r;
}

extern "C" void kernel_launch(void* const* d_in, const int* in_sizes, int n_in,
                              void* d_out, int out_size, void* d_ws, size_t ws_size,
                              hipStream_t stream) {
  const float* x      = (const float*)d_in[0];
  const float* b10    = (const float*)d_in[1];
  const float* w1     = (const float*)d_in[2];
  const float* gamma1 = (const float*)d_in[3];
  const float* beta1  = (const float*)d_in[4];
  const float* b11    = (const float*)d_in[5];
  const float* a1     = (const float*)d_in[6];
  const float* b12    = (const float*)d_in[7];
  const float* b20    = (const float*)d_in[8];
  const float* w2     = (const float*)d_in[9];
  const float* gamma2 = (const float*)d_in[10];
  const float* beta2  = (const float*)d_in[11];
  const float* b21    = (const float*)d_in[12];
  const float* a2     = (const float*)d_in[13];
  const float* b22    = (const float*)d_in[14];
  float* out = (float*)d_out;

  char* ws = (char*)d_ws;
  unsigned long long* stats = (unsigned long long*)(ws + OFF_STATS);
  float* scales = (float*)(ws + OFF_SCALES);
  float* AB     = (float*)(ws + OFF_AB);
  char*  wpk1   = ws + OFF_WPK1;
  char*  wpk2   = ws + OFF_WPK2;
  char*  spad   = ws + OFF_SPAD;
  short* cout   = (short*)(ws + OFF_COUT);

  hipMemsetAsync(spad, 0, SPAD_BYTES, stream);
  hipMemsetAsync(stats, 0, 8192, stream);

  k_wprep<<<2304, 256, 0, stream>>>(w1, wpk1);
  k_wprep<<<2304, 256, 0, stream>>>(w2, wpk2);
  k_scale<<<256, 256, 0, stream>>>(w1, scales);
  k_scale<<<256, 256, 0, stream>>>(w2, scales + 256);

  k_e0<<<1792, 256, 0, stream>>>(x, b10, spad);
  k_conv<<<896, 512, 0, stream>>>(spad, wpk1, cout, stats);
  k_bnprep<<<1, 256, 0, stream>>>(stats, scales, gamma1, beta1, AB);
  k_e1<<<1792, 256, 0, stream>>>(cout, x, AB, b11, a1, b12, b20, out, spad);
  k_conv<<<896, 512, 0, stream>>>(spad, wpk2, cout, stats + 512);
  k_bnprep<<<1, 256, 0, stream>>>(stats + 512, scales + 256, gamma2, beta2, AB + 512);
  k_e2<<<12544, 256, 0, stream>>>(cout, AB + 512, b21, a2, b22, out);
}

// Round 11
// 245.368 us; speedup vs baseline: 1.3763x; 1.3763x over previous
//
#include <hip/hip_runtime.h>

using i32x4 = __attribute__((ext_vector_type(4))) int;

// ws layout (bytes); total = 41,629,696 B
#define OFF_STATS  0u         // 1024 x u64: [0..511] conv1 (s1,s2), [512..1023] conv2
#define OFF_SCALES 8192u      // 512 f32
#define OFF_AB     10240u     // 1024 f32
#define OFF_WPK1   14336u     // 589824 B int8
#define OFF_WPK2   604160u    // 589824 B int8
#define OFF_SPAD   1193984u   // 64*30*30*256 int8 = 14,745,600 B
#define OFF_COUT   15939584u  // 64*256*28*28 int16 = 25,690,112 B
#define SPAD_BYTES (64ull * 30 * 30 * 256)

__device__ __forceinline__ char sgn8(float v) {
  return v > 0.f ? (char)1 : (v < 0.f ? (char)-1 : (char)0);
}

// pack sign(w) into i8-MFMA A-fragment order: [khw][cc][mb][lane][i]
// o = mb*16 + (lane&15), c = cc*64 + (lane>>4)*16 + i  (mirrors B's NHWC layout)
__global__ __launch_bounds__(256) void k_wprep(const float* __restrict__ w,
                                               char* __restrict__ wp) {
  int idx  = blockIdx.x * 256 + threadIdx.x;  // < 589824
  int i    = idx & 15;
  int lane = (idx >> 4) & 63;
  int mb   = (idx >> 10) & 15;
  int cc   = (idx >> 14) & 3;
  int khw  = idx >> 16;
  int o = mb * 16 + (lane & 15);
  int c = cc * 64 + (lane >> 4) * 16 + i;
  int kh = khw / 3, kw = khw % 3;
  float v = w[(((size_t)o * 256 + c) * 3 + kh) * 3 + kw];
  wp[idx] = sgn8(v);
}

__global__ __launch_bounds__(256) void k_scale(const float* __restrict__ w,
                                               float* __restrict__ sc) {
  int o = blockIdx.x;
  float s = 0.f;
  for (int i = threadIdx.x; i < 2304; i += 256) s += fabsf(w[(size_t)o * 2304 + i]);
  for (int m = 1; m < 64; m <<= 1) s += __shfl_xor(s, m);
  __shared__ float red[4];
  if ((threadIdx.x & 63) == 0) red[threadIdx.x >> 6] = s;
  __syncthreads();
  if (threadIdx.x == 0) sc[o] = (red[0] + red[1] + red[2] + red[3]) * (1.f / 2304.f);
}

// sign(x + b10) -> padded NHWC int8 sign tensor [64][30][30][256] (border stays 0)
__global__ __launch_bounds__(256) void k_e0(const float* __restrict__ x,
                                            const float* __restrict__ b10,
                                            char* __restrict__ sp) {
  __shared__ char lds[28 * 260];
  int img = blockIdx.x / 28, y = blockIdx.x % 28;
  int t = threadIdx.x;
  int xx = t & 31, ci = t >> 5;
  for (int c0 = 0; c0 < 256; c0 += 8) {
    int c = c0 + ci;
    if (xx < 28) {
      float v = x[(((size_t)img * 256 + c) * 28 + y) * 28 + xx] + b10[c];
      lds[xx * 260 + c] = sgn8(v);
    }
  }
  __syncthreads();
  size_t base = (((size_t)img * 30 + (y + 1)) * 30 + 1) * 256;  // byte offset
  int* spi = (int*)(sp + base);
  for (int q = t; q < 1792; q += 256) {
    int xo = q >> 6, c4 = (q & 63) << 2;
    spi[q] = *(const int*)&lds[xo * 260 + c4];
  }
}

// binary conv as implicit GEMM with i8 MFMA (exact int32 counts).
// Occupancy-doubling variant of the proven j=7 body: block = 1 image x
// 4 output rows (112 px) x 128 out-ch (bh half). 8 waves, wave = 16 out-ch
// (mi=1) x 112 px. Grid = 64*7*2 = 896 x 512 thr = 7168 waves (2x round 9).
// S-tile 6x30x256 = 45KB LDS -> 3 blocks/CU resident (24 waves/CU target).
// Exact swizzle: stored granule g' = g ^ k(tp), k(tp) = (tp-2*(tp/30))&15
// == (28*row+col)&15; read key (l15+12*kh+kw)&15 == k(tp) -> bijective per
// 16-lane group => conflict-light ds_read_b128.
// __launch_bounds__(512,4): j=7 bodies compile to 64-68 VGPR spill-free
// under this cap (rounds 4/9); j=4 small-tile bodies always collapse to
// VGPR=40+spills (rounds 6/7/10) — do not shrink the tile again.
__global__ __launch_bounds__(512, 4) void k_conv(const char* __restrict__ S,
                                                 const char* __restrict__ Wp,
                                                 short* __restrict__ C,
                                                 unsigned long long* __restrict__ stats) {
  __shared__ char lds[46080];
  int bid = blockIdx.x;            // 896 = 64 img * 7 ytile * 2 bh
  int img = bid / 14;
  int r14 = bid % 14;
  int yt  = r14 >> 1;
  int bh  = r14 & 1;
  int tid = threadIdx.x;
  int wave = tid >> 6, lane = tid & 63;
  int l15 = lane & 15, lg = lane >> 4;
  int y0 = yt * 4;

  // stage 6 padded rows y0..y0+5 (local tp = row*30+col, 180 px x 16 granules)
  const char* sb = S + (size_t)img * 230400 + (size_t)y0 * 7680;
  for (int q = tid; q < 2880; q += 512) {
    int tp = q >> 4;
    int g  = q & 15;
    int k  = (tp - 2 * (tp / 30)) & 15;   // == (28*row + col) & 15
    int4 v = *reinterpret_cast<const int4*>(sb + tp * 256 + g * 16);
    *reinterpret_cast<int4*>(&lds[tp * 256 + ((g ^ k) << 4)]) = v;
  }
  __syncthreads();

  int pixtp[7];
#pragma unroll
  for (int j = 0; j < 7; ++j) {
    int p = j * 16 + l15;
    pixtp[j] = (p / 28) * 30 + (p % 28);   // local tile pixel, rows 0..3
  }
  i32x4 acc[7] = {};
  int mb = bh * 8 + wave;                  // A-fragment o-block (16 ch)

#pragma unroll 1
  for (int kh = 0; kh < 3; ++kh) {
#pragma unroll
    for (int kw = 0; kw < 3; ++kw) {
      int khw = kh * 3 + kw;
      int shift = kh * 30 + kw;
      int kk = (l15 + 12 * kh + kw) & 15;
      const char* ab = Wp + (size_t)khw * 65536 + (size_t)mb * 1024 + lane * 16;
#pragma unroll
      for (int cc = 0; cc < 4; ++cc) {
        i32x4 afr = *reinterpret_cast<const i32x4*>(ab + cc * 16384);
        int gr = (lg + 4 * cc) ^ kk;
        i32x4 bfr[7];
#pragma unroll
        for (int j = 0; j < 7; ++j) {
          int tp = pixtp[j] + shift;
          bfr[j] = *reinterpret_cast<const i32x4*>(&lds[tp * 256 + (gr << 4)]);
        }
#pragma unroll
        for (int j = 0; j < 7; ++j)
          acc[j] = __builtin_amdgcn_mfma_i32_16x16x64_i8(afr, bfr[j], acc[j], 0, 0, 0);
      }
    }
  }

  short* cb = C + (size_t)img * 200704;
#pragma unroll
  for (int r = 0; r < 4; ++r) {
    int o = bh * 128 + wave * 16 + lg * 4 + r;
    int s1 = 0;
    long long s2 = 0;
#pragma unroll
    for (int j = 0; j < 7; ++j) {
      int iv = acc[j][r];
      int p = j * 16 + l15;
      cb[(size_t)o * 784 + (y0 + p / 28) * 28 + (p % 28)] = (short)iv;
      s1 += iv;
      s2 += (long long)iv * iv;
    }
    long long t1 = s1, t2 = s2;
#pragma unroll
    for (int m = 1; m < 16; m <<= 1) {
      t1 += __shfl_xor(t1, m);
      t2 += __shfl_xor(t2, m);
    }
    if (l15 == 0) {
      atomicAdd(&stats[o], (unsigned long long)t1);
      atomicAdd(&stats[256 + o], (unsigned long long)t2);
    }
  }
}

// fold scale + BN(train) into per-channel affine: bn(scale*I) = A*I + B
__global__ void k_bnprep(const unsigned long long* __restrict__ stats,
                         const float* __restrict__ scale,
                         const float* __restrict__ gamma,
                         const float* __restrict__ beta,
                         float* __restrict__ AB) {
  int o = threadIdx.x;
  long long s1 = (long long)stats[o];
  long long s2 = (long long)stats[256 + o];
  double n  = 50176.0;
  double sc = (double)scale[o];
  double mI = (double)s1 / n;
  double vI = (double)s2 / n - mI * mI;
  double mu  = sc * mI;
  double var = sc * sc * vI;
  double r = 1.0 / sqrt(var + 1e-5);
  double g = (double)gamma[o];
  AB[o]       = (float)(g * sc * r);
  AB[256 + o] = (float)((double)beta[o] - g * r * mu);
}

// h = prelu(bn1(c1) + x + b11, a1) + b12 -> d_out; sign(h+b20) -> spad
__global__ __launch_bounds__(256) void k_e1(const short* __restrict__ c1,
                                            const float* __restrict__ x,
                                            const float* __restrict__ AB,
                                            const float* __restrict__ b11,
                                            const float* __restrict__ a1,
                                            const float* __restrict__ b12,
                                            const float* __restrict__ b20,
                                            float* __restrict__ ho,
                                            char* __restrict__ sp) {
  __shared__ char lds[28 * 260];
  int img = blockIdx.x / 28, y = blockIdx.x % 28;
  int t = threadIdx.x;
  int xx = t & 31, ci = t >> 5;
  for (int c0 = 0; c0 < 256; c0 += 8) {
    int c = c0 + ci;
    if (xx < 28) {
      size_t off = (((size_t)img * 256 + c) * 28 + y) * 28 + xx;
      float h = AB[c] * (float)c1[off] + AB[256 + c] + x[off] + b11[c];
      h = h >= 0.f ? h : a1[c] * h;
      h += b12[c];
      ho[off] = h;
      lds[xx * 260 + c] = sgn8(h + b20[c]);
    }
  }
  __syncthreads();
  size_t base = (((size_t)img * 30 + (y + 1)) * 30 + 1) * 256;
  int* spi = (int*)(sp + base);
  for (int q = t; q < 1792; q += 256) {
    int xo = q >> 6, c4 = (q & 63) << 2;
    spi[q] = *(const int*)&lds[xo * 260 + c4];
  }
}

// y = prelu(bn2(c2) + h + b21, a2) + b22, in place on d_out (h)
__global__ __launch_bounds__(256) void k_e2(const short* __restrict__ c2,
                                            const float* __restrict__ AB2,
                                            const float* __restrict__ b21,
                                            const float* __restrict__ a2,
                                            const float* __restrict__ b22,
                                            float* __restrict__ io) {
  int v = blockIdx.x * 256 + threadIdx.x;  // < 3211264 float4s
  int c = ((v * 4) / 784) & 255;
  float A = AB2[c], B = AB2[256 + c];
  float p21 = b21[c], aa = a2[c], p22 = b22[c];
  short4 I = reinterpret_cast<const short4*>(c2)[v];
  float4 h = reinterpret_cast<const float4*>(io)[v];
  float4 r;
  float t0 = A * (float)I.x + B + h.x + p21; t0 = t0 >= 0.f ? t0 : aa * t0; r.x = t0 + p22;
  float t1 = A * (float)I.y + B + h.y + p21; t1 = t1 >= 0.f ? t1 : aa * t1; r.y = t1 + p22;
  float t2 = A * (float)I.z + B + h.z + p21; t2 = t2 >= 0.f ? t2 : aa * t2; r.z = t2 + p22;
  float t3 = A * (float)I.w + B + h.w + p21; t3 = t3 >= 0.f ? t3 : aa * t3; r.w = t3 + p22;
  reinterpret_cast<float4*>(io)[v] = r;
}

extern "C" void kernel_launch(void* const* d_in, const int* in_sizes, int n_in,
                              void* d_out, int out_size, void* d_ws, size_t ws_size,
                              hipStream_t stream) {
  const float* x      = (const float*)d_in[0];
  const float* b10    = (const float*)d_in[1];
  const float* w1     = (const float*)d_in[2];
  const float* gamma1 = (const float*)d_in[3];
  const float* beta1  = (const float*)d_in[4];
  const float* b11    = (const float*)d_in[5];
  const float* a1     = (const float*)d_in[6];
  const float* b12    = (const float*)d_in[7];
  const float* b20    = (const float*)d_in[8];
  const float* w2     = (const float*)d_in[9];
  const float* gamma2 = (const float*)d_in[10];
  const float* beta2  = (const float*)d_in[11];
  const float* b21    = (const float*)d_in[12];
  const float* a2     = (const float*)d_in[13];
  const float* b22    = (const float*)d_in[14];
  float* out = (float*)d_out;

  char* ws = (char*)d_ws;
  unsigned long long* stats = (unsigned long long*)(ws + OFF_STATS);
  float* scales = (float*)(ws + OFF_SCALES);
  float* AB     = (float*)(ws + OFF_AB);
  char*  wpk1   = ws + OFF_WPK1;
  char*  wpk2   = ws + OFF_WPK2;
  char*  spad   = ws + OFF_SPAD;
  short* cout   = (short*)(ws + OFF_COUT);

  hipMemsetAsync(spad, 0, SPAD_BYTES, stream);
  hipMemsetAsync(stats, 0, 8192, stream);

  k_wprep<<<2304, 256, 0, stream>>>(w1, wpk1);
  k_wprep<<<2304, 256, 0, stream>>>(w2, wpk2);
  k_scale<<<256, 256, 0, stream>>>(w1, scales);
  k_scale<<<256, 256, 0, stream>>>(w2, scales + 256);

  k_e0<<<1792, 256, 0, stream>>>(x, b10, spad);
  k_conv<<<896, 512, 0, stream>>>(spad, wpk1, cout, stats);
  k_bnprep<<<1, 256, 0, stream>>>(stats, scales, gamma1, beta1, AB);
  k_e1<<<1792, 256, 0, stream>>>(cout, x, AB, b11, a1, b12, b20, out, spad);
  k_conv<<<896, 512, 0, stream>>>(spad, wpk2, cout, stats + 512);
  k_bnprep<<<1, 256, 0, stream>>>(stats + 512, scales + 256, gamma2, beta2, AB + 512);
  k_e2<<<12544, 256, 0, stream>>>(cout, AB + 512, b21, a2, b22, out);
}